// Round 5
// baseline (157.038 us; speedup 1.0000x reference)
//
#include <hip/hip_runtime.h>

#define N 8192
#define KD 128
#define NCLS 10
#define NCH 16
#define CHUNK (N / NCH)   /* 512 cols per block */
#define NJ (CHUNK / 64)   /* 8 jj tiles of 64 cols */

typedef __attribute__((ext_vector_type(8))) short short8;
typedef __attribute__((ext_vector_type(4))) float floatx4;

__device__ __forceinline__ unsigned short f2bf(float x) {
    unsigned u = __float_as_uint(x);
    u += 0x7fffu + ((u >> 16) & 1u);   // round-to-nearest-even
    return (unsigned short)(u >> 16);
}

// ---------------- k_conv: bf16 convert (B1 swizzled) + diag | class sums + counts ----
// blocks 0..511: convert 16 rows each.  blocks 512..575: class-sum 128 rows each.
__global__ __launch_bounds__(256) void k_conv(const float* __restrict__ F,
                                              const int* __restrict__ tgt,
                                              float* __restrict__ diag10,
                                              unsigned short* __restrict__ A10,
                                              unsigned short* __restrict__ B1,
                                              float* __restrict__ S,
                                              int* __restrict__ cnt) {
    int t = threadIdx.x;
    if (blockIdx.x < 512) {
        int row0 = blockIdx.x * 16;
        int col4 = t & 31;   // which float4 of the row
        int rg = t >> 5;     // 0..7
#pragma unroll
        for (int sw = 0; sw < 2; ++sw) {
            int row = row0 + sw * 8 + rg;
            float4 v = *(const float4*)(F + (size_t)row * KD + col4 * 4);
            float sq = v.x * v.x + v.y * v.y + v.z * v.z + v.w * v.w;
#pragma unroll
            for (int off = 16; off >= 1; off >>= 1) sq += __shfl_xor(sq, off);
            if (col4 == 0) diag10[row] = 10.f * sq;
            ushort4 a, b;
            a.x = f2bf(10.f * v.x); a.y = f2bf(10.f * v.y);
            a.z = f2bf(10.f * v.z); a.w = f2bf(10.f * v.w);
            b.x = f2bf(v.x); b.y = f2bf(v.y); b.z = f2bf(v.z); b.w = f2bf(v.w);
            *(ushort4*)(A10 + (size_t)row * KD + col4 * 4) = a;
            // B1: XOR-swizzled 16B blocks within each row (kb -> kb ^ (row&15))
            int kb = col4 >> 1, half = col4 & 1;
            int swo = ((kb ^ (row & 15)) << 3) + (half << 2);
            *(ushort4*)(B1 + (size_t)row * KD + swo) = b;
        }
    } else {
        int b = blockIdx.x - 512;          // 0..63
        int row0 = b * 128;
        int k = t & 127, h = t >> 7;
        __shared__ int lh[NCLS];
        if (t < NCLS) lh[t] = 0;
        __syncthreads();
        if (t < 128) atomicAdd(&lh[tgt[row0 + t]], 1);
        float local[NCLS];
#pragma unroll
        for (int c = 0; c < NCLS; ++c) local[c] = 0.f;
        for (int ii = 0; ii < 64; ++ii) {
            int row = row0 + h * 64 + ii;
            float v = F[(size_t)row * KD + k];
            int c = tgt[row];
#pragma unroll
            for (int cc = 0; cc < NCLS; ++cc) local[cc] += (cc == c) ? v : 0.f;
        }
        __shared__ float red[2][NCLS][KD];   // 10 KiB
#pragma unroll
        for (int cc = 0; cc < NCLS; ++cc) red[h][cc][k] = local[cc];
        __syncthreads();
        if (h == 0) {
#pragma unroll
            for (int cc = 0; cc < NCLS; ++cc)
                atomicAdd(&S[cc * KD + k], red[0][cc][k] + red[1][cc][k]);
            if (t < NCLS) atomicAdd(&cnt[t], lh[t]);
        }
    }
}

// ---------------- k_pair: pure MFMA sweep + rare exp cold-path --------------------
// Grid (32, 16). Block = 256 rows x 64 cols; 4 waves in 2x2: wave = 128 rows x 32 cols.
__global__ __launch_bounds__(256, 2) void k_pair(const unsigned short* __restrict__ A10,
                                                 const unsigned short* __restrict__ B1,
                                                 const float* __restrict__ diag10,
                                                 float* __restrict__ PS) {
    __shared__ unsigned short Bs[2][64 * KD];   // 2 x 16 KiB
    __shared__ float wmin[4];
    int bx = blockIdx.x, ch = blockIdx.y;
    int tid = threadIdx.x;
    int wid = tid >> 6, lane = tid & 63;
    int quad = lane >> 4, l16 = lane & 15;
    int wr = wid >> 1, wc = wid & 1;
    int rowB = bx * 256;
    int row0w = rowB + wr * 128;    // this wave's 128 rows

    // block-min of diag10 over the 256 rows -> skip threshold
    float d = diag10[rowB + tid];
#pragma unroll
    for (int off = 32; off >= 1; off >>= 1) d = fminf(d, __shfl_xor(d, off));
    if (lane == 0) wmin[wid] = d;

    // stage jj=0
    {
        const unsigned char* g = (const unsigned char*)B1 +
            ((size_t)(ch * CHUNK) * KD) * 2 + wid * 4096 + lane * 16;
        unsigned char* l = (unsigned char*)&Bs[0][0] + wid * 4096;
#pragma unroll
        for (int i = 0; i < 4; ++i)
            __builtin_amdgcn_global_load_lds(
                (const __attribute__((address_space(1))) void*)(g + i * 1024),
                (__attribute__((address_space(3))) void*)(l + i * 1024), 16, 0, 0);
    }

    // A fragments resident: af[ti][ks], rows row0w + ti*16 + l16  (128 VGPRs)
    short8 af[8][4];
#pragma unroll
    for (int ti = 0; ti < 8; ++ti)
#pragma unroll
        for (int ks = 0; ks < 4; ++ks)
            af[ti][ks] = *(const short8*)(A10 +
                (size_t)(row0w + ti * 16 + l16) * KD + ks * 32 + quad * 8);

    asm volatile("s_waitcnt vmcnt(0)" ::: "memory");
    __syncthreads();
    float thr = fminf(fminf(wmin[0], wmin[1]), fminf(wmin[2], wmin[3])) - 60.f;

    for (int jj = 0; jj < NJ; ++jj) {
        if (jj + 1 < NJ) {
            const unsigned char* g = (const unsigned char*)B1 +
                ((size_t)(ch * CHUNK + (jj + 1) * 64) * KD) * 2 + wid * 4096 + lane * 16;
            unsigned char* l = (unsigned char*)&Bs[(jj + 1) & 1][0] + wid * 4096;
#pragma unroll
            for (int i = 0; i < 4; ++i)
                __builtin_amdgcn_global_load_lds(
                    (const __attribute__((address_space(1))) void*)(g + i * 1024),
                    (__attribute__((address_space(3))) void*)(l + i * 1024), 16, 0, 0);
        }

        const unsigned short* bs = &Bs[jj & 1][0];
        floatx4 acc[8][2];
#pragma unroll
        for (int ti = 0; ti < 8; ++ti)
#pragma unroll
            for (int tj = 0; tj < 2; ++tj)
                acc[ti][tj] = (floatx4){0.f, 0.f, 0.f, 0.f};

#pragma unroll
        for (int ks = 0; ks < 4; ++ks) {
            short8 bfr[2];
#pragma unroll
            for (int tj = 0; tj < 2; ++tj) {
                int lr = wc * 32 + tj * 16 + l16;
                bfr[tj] = *(const short8*)(bs + lr * KD + (((ks * 4 + quad) ^ l16) << 3));
            }
#pragma unroll
            for (int ti = 0; ti < 8; ++ti)
#pragma unroll
                for (int tj = 0; tj < 2; ++tj)
                    acc[ti][tj] = __builtin_amdgcn_mfma_f32_16x16x32_bf16(
                        af[ti][ks], bfr[tj], acc[ti][tj], 0, 0, 0);
        }

        // tree-max over this lane's 64 values
        float m2[8];
#pragma unroll
        for (int ti = 0; ti < 8; ++ti) {
            float a = fmaxf(fmaxf(acc[ti][0][0], acc[ti][0][1]),
                            fmaxf(acc[ti][0][2], acc[ti][0][3]));
            float b = fmaxf(fmaxf(acc[ti][1][0], acc[ti][1][1]),
                            fmaxf(acc[ti][1][2], acc[ti][1][3]));
            m2[ti] = fmaxf(a, b);
        }
        float mx = fmaxf(fmaxf(fmaxf(m2[0], m2[1]), fmaxf(m2[2], m2[3])),
                         fmaxf(fmaxf(m2[4], m2[5]), fmaxf(m2[6], m2[7])));

        if (__any(mx > thr)) {
            // cold path: only diagonal tiles in practice
            int col0 = ch * CHUNK + jj * 64 + wc * 32;
#pragma unroll
            for (int ti = 0; ti < 8; ++ti)
#pragma unroll
                for (int r = 0; r < 4; ++r) {
                    int grow = row0w + ti * 16 + quad * 4 + r;
                    float Mrow = diag10[grow];
                    float rs = 0.f;
#pragma unroll
                    for (int tj = 0; tj < 2; ++tj) {
                        int gcol = col0 + tj * 16 + l16;
                        float ev = __expf(acc[ti][tj][r] - Mrow);
                        rs += (grow == gcol) ? 0.f : ev;
                    }
                    rs += __shfl_xor(rs, 1, 16);
                    rs += __shfl_xor(rs, 2, 16);
                    rs += __shfl_xor(rs, 4, 16);
                    rs += __shfl_xor(rs, 8, 16);
                    if (l16 == 0) atomicAdd(&PS[grow], rs);
                }
        }

        asm volatile("s_waitcnt vmcnt(0)" ::: "memory");
        __syncthreads();
    }
}

// ---------------- k_final: posdot via S, log-term, reduce, ticket finalize -------
__global__ __launch_bounds__(256) void k_final(const float* __restrict__ F,
                                               const int* __restrict__ tgt,
                                               const float* __restrict__ diag10,
                                               const float* __restrict__ PS,
                                               const float* __restrict__ S,
                                               int* __restrict__ cnt,
                                               float* __restrict__ acc,
                                               float* __restrict__ out) {
    __shared__ float Ss[NCLS * KD];
    __shared__ int cs[NCLS];
    int t = threadIdx.x;
    for (int i = t; i < NCLS * KD; i += 256) Ss[i] = S[i];
    if (t < NCLS) cs[t] = cnt[t];
    __syncthreads();

    int g = t >> 2, q = t & 3;            // 4 lanes per row
    int row = blockIdx.x * 64 + g;
    int c = tgt[row];
    float dot = 0.f;
#pragma unroll
    for (int i = 0; i < 8; ++i) {
        float4 f = *(const float4*)(F + (size_t)row * KD + i * 16 + q * 4);
        float4 s = *(const float4*)(Ss + c * KD + i * 16 + q * 4);
        dot += f.x * s.x + f.y * s.y + f.z * s.z + f.w * s.w;
    }
    dot += __shfl_xor(dot, 1, 4);
    dot += __shfl_xor(dot, 2, 4);

    float mlp = 0.f;
    if (q == 0) {
        float M = diag10[row];
        float pp = 10.f * dot - M;            // sum over positives of logits
        float T = PS[row];                    // surviving exp mass (==0 here)
        float np = (float)(cs[c] - 1);
        mlp = (np < 0.5f) ? 0.f : (pp - np * (M + __logf(T + 1e-20f))) / np;
    }
#pragma unroll
    for (int off = 32; off >= 1; off >>= 1) mlp += __shfl_xor(mlp, off);
    __shared__ float wsum[4];
    int lane = t & 63, w = t >> 6;
    if (lane == 0) wsum[w] = mlp;
    __syncthreads();
    if (t == 0) {
        atomicAdd(acc, (wsum[0] + wsum[1]) + (wsum[2] + wsum[3]));
        __threadfence();
        int old = atomicAdd(&cnt[12], 1);   // ticket
        if (old == (int)gridDim.x - 1) {
            float tot = atomicAdd(acc, 0.0f);   // coherent read of total
            double sp = 0.0, sn = 0.0;
            for (int cc = 0; cc < NCLS; ++cc) {
                double n = (double)cs[cc];
                sp += n * (n - 1.0);
                sn += n * ((double)N - n);
            }
            out[0] = (float)(-(0.1 / 0.07) * ((double)tot / (double)N));
            out[1] = (float)(sp / (double)N);
            out[2] = (float)(sn / (double)N);
        }
    }
}

extern "C" void kernel_launch(void* const* d_in, const int* in_sizes, int n_in,
                              void* d_out, int out_size, void* d_ws, size_t ws_size,
                              hipStream_t stream) {
    const float* F = (const float*)d_in[0];
    const int* tgt = (const int*)d_in[1];
    float* out = (float*)d_out;
    char* ws = (char*)d_ws;

    int* cnt = (int*)(ws);                       // 64 B (ticket at cnt[12])
    float* acc = (float*)(ws + 64);              // 4 B
    float* S = (float*)(ws + 128);               // 5120 B
    float* PS = (float*)(ws + 8192);             // 32 KiB  -> ends 40960
    float* diag10 = (float*)(ws + 65536);        // 32 KiB
    unsigned short* A10 = (unsigned short*)(ws + (1u << 20));   // 2 MiB
    unsigned short* B1 = (unsigned short*)(ws + (3u << 20));    // 2 MiB

    hipMemsetAsync(ws, 0, 40960, stream);        // cnt + acc + S + PS
    k_conv<<<576, 256, 0, stream>>>(F, tgt, diag10, A10, B1, S, cnt);
    k_pair<<<dim3(N / 256, NCH), 256, 0, stream>>>(A10, B1, diag10, PS);
    k_final<<<N / 64, 256, 0, stream>>>(F, tgt, diag10, PS, S, cnt, acc, out);
}

// Round 6
// 101.176 us; speedup vs baseline: 1.5521x; 1.5521x over previous
//
#include <hip/hip_runtime.h>

#define N 8192
#define KD 128
#define NCLS 10
#define NCH 8
#define CHUNK (N / NCH)   /* 1024 cols per block */
#define NJ (CHUNK / 128)  /* 8 jj tiles of 128 cols */

typedef __attribute__((ext_vector_type(8))) short short8;
typedef __attribute__((ext_vector_type(4))) float floatx4;

__device__ __forceinline__ unsigned short f2bf(float x) {
    unsigned u = __float_as_uint(x);
    u += 0x7fffu + ((u >> 16) & 1u);   // round-to-nearest-even
    return (unsigned short)(u >> 16);
}

// ---------------- k_conv: bf16 convert (B1 swizzled) + diag | class sums + counts ----
// blocks 0..511: convert 16 rows each.  blocks 512..575: class-sum 128 rows each.
__global__ __launch_bounds__(256) void k_conv(const float* __restrict__ F,
                                              const int* __restrict__ tgt,
                                              float* __restrict__ diag10,
                                              unsigned short* __restrict__ A10,
                                              unsigned short* __restrict__ B1,
                                              float* __restrict__ S,
                                              int* __restrict__ cnt) {
    int t = threadIdx.x;
    if (blockIdx.x < 512) {
        int row0 = blockIdx.x * 16;
        int col4 = t & 31;   // which float4 of the row
        int rg = t >> 5;     // 0..7
#pragma unroll
        for (int sw = 0; sw < 2; ++sw) {
            int row = row0 + sw * 8 + rg;
            float4 v = *(const float4*)(F + (size_t)row * KD + col4 * 4);
            float sq = v.x * v.x + v.y * v.y + v.z * v.z + v.w * v.w;
#pragma unroll
            for (int off = 16; off >= 1; off >>= 1) sq += __shfl_xor(sq, off);
            if (col4 == 0) diag10[row] = 10.f * sq;
            ushort4 a, b;
            a.x = f2bf(10.f * v.x); a.y = f2bf(10.f * v.y);
            a.z = f2bf(10.f * v.z); a.w = f2bf(10.f * v.w);
            b.x = f2bf(v.x); b.y = f2bf(v.y); b.z = f2bf(v.z); b.w = f2bf(v.w);
            *(ushort4*)(A10 + (size_t)row * KD + col4 * 4) = a;
            // B1: XOR-swizzled 16B blocks within each row (kb -> kb ^ (row&15))
            int kb = col4 >> 1, half = col4 & 1;
            int swo = ((kb ^ (row & 15)) << 3) + (half << 2);
            *(ushort4*)(B1 + (size_t)row * KD + swo) = b;
        }
    } else {
        int b = blockIdx.x - 512;          // 0..63
        int row0 = b * 128;
        int k = t & 127, h = t >> 7;
        __shared__ int lh[NCLS];
        if (t < NCLS) lh[t] = 0;
        __syncthreads();
        if (t < 128) atomicAdd(&lh[tgt[row0 + t]], 1);
        float local[NCLS];
#pragma unroll
        for (int c = 0; c < NCLS; ++c) local[c] = 0.f;
        for (int ii = 0; ii < 64; ++ii) {
            int row = row0 + h * 64 + ii;
            float v = F[(size_t)row * KD + k];
            int c = tgt[row];
#pragma unroll
            for (int cc = 0; cc < NCLS; ++cc) local[cc] += (cc == c) ? v : 0.f;
        }
        __shared__ float red[2][NCLS][KD];   // 10 KiB
#pragma unroll
        for (int cc = 0; cc < NCLS; ++cc) red[h][cc][k] = local[cc];
        __syncthreads();
        if (h == 0) {
#pragma unroll
            for (int cc = 0; cc < NCLS; ++cc)
                atomicAdd(&S[cc * KD + k], red[0][cc][k] + red[1][cc][k]);
            if (t < NCLS) atomicAdd(&cnt[t], lh[t]);
        }
    }
}

// ---------------- k_pair: pure-MFMA sweep, rare exp cold path -----------------------
// Grid (64, 8). Block 256 = 4 waves in 2x2; wave tile 64x64; per jj a 128x128 B tile
// is DMA-staged to LDS (double-buffered, XOR-swizzled). Hot loop: MFMA + max tree.
__global__ __launch_bounds__(256, 2) void k_pair(const unsigned short* __restrict__ A10,
                                                 const unsigned short* __restrict__ B1,
                                                 const float* __restrict__ diag10,
                                                 float* __restrict__ PS) {
    __shared__ unsigned short Bs[2][128 * KD];   // 2 x 32 KiB = 64 KiB
    int bx = blockIdx.x, ch = blockIdx.y;
    int tid = threadIdx.x;
    int wid = tid >> 6, lane = tid & 63;
    int quad = lane >> 4, l16 = lane & 15;
    int wr = wid >> 1, wc = wid & 1;
    int row0w = bx * 128 + wr * 64;              // this wave's 64 rows

    // stage jj=0 (32 KiB, whole block; 8 x 1 KiB per wave)
    {
        const unsigned char* g = (const unsigned char*)B1 +
            (size_t)(ch * CHUNK) * KD * 2 + wid * 1024 + lane * 16;
        unsigned char* l = (unsigned char*)&Bs[0][0] + wid * 1024;
#pragma unroll
        for (int i = 0; i < 8; ++i)
            __builtin_amdgcn_global_load_lds(
                (const __attribute__((address_space(1))) void*)(g + i * 4096),
                (__attribute__((address_space(3))) void*)(l + i * 4096), 16, 0, 0);
    }

    // per-wave skip threshold: min over this wave's 64 rows of diag10, minus 60
    float d = diag10[row0w + lane];
#pragma unroll
    for (int off = 32; off >= 1; off >>= 1) d = fminf(d, __shfl_xor(d, off));
    float thr = d - 60.f;

    // A fragments resident: af[ti][ks], rows row0w + ti*16 + l16 (64 VGPRs)
    short8 af[4][4];
#pragma unroll
    for (int ti = 0; ti < 4; ++ti)
#pragma unroll
        for (int ks = 0; ks < 4; ++ks)
            af[ti][ks] = *(const short8*)(A10 +
                (size_t)(row0w + ti * 16 + l16) * KD + ks * 32 + quad * 8);

    asm volatile("s_waitcnt vmcnt(0)" ::: "memory");
    __syncthreads();

    for (int jj = 0; jj < NJ; ++jj) {
        // prefetch next 128-col tile into the other buffer
        if (jj + 1 < NJ) {
            const unsigned char* g = (const unsigned char*)B1 +
                (size_t)(ch * CHUNK + (jj + 1) * 128) * KD * 2 + wid * 1024 + lane * 16;
            unsigned char* l = (unsigned char*)&Bs[(jj + 1) & 1][0] + wid * 1024;
#pragma unroll
            for (int i = 0; i < 8; ++i)
                __builtin_amdgcn_global_load_lds(
                    (const __attribute__((address_space(1))) void*)(g + i * 4096),
                    (__attribute__((address_space(3))) void*)(l + i * 4096), 16, 0, 0);
        }

        const unsigned short* bs = &Bs[jj & 1][0];
        floatx4 acc[4][4];
#pragma unroll
        for (int ti = 0; ti < 4; ++ti)
#pragma unroll
            for (int tj = 0; tj < 4; ++tj)
                acc[ti][tj] = (floatx4){0.f, 0.f, 0.f, 0.f};

#pragma unroll
        for (int ks = 0; ks < 4; ++ks) {
            short8 bfr[4];
#pragma unroll
            for (int tj = 0; tj < 4; ++tj) {
                int lr = wc * 64 + tj * 16 + l16;                 // local col index
                bfr[tj] = *(const short8*)(bs + lr * KD + (((ks * 4 + quad) ^ l16) << 3));
            }
#pragma unroll
            for (int ti = 0; ti < 4; ++ti)
#pragma unroll
                for (int tj = 0; tj < 4; ++tj)
                    acc[ti][tj] = __builtin_amdgcn_mfma_f32_16x16x32_bf16(
                        af[ti][ks], bfr[tj], acc[ti][tj], 0, 0, 0);
        }

        // max tree over this lane's 64 accumulator values
        float mx = -1e30f;
#pragma unroll
        for (int ti = 0; ti < 4; ++ti)
#pragma unroll
            for (int tj = 0; tj < 4; ++tj) {
                float a01 = fmaxf(acc[ti][tj][0], acc[ti][tj][1]);
                float a23 = fmaxf(acc[ti][tj][2], acc[ti][tj][3]);
                mx = fmaxf(mx, fmaxf(a01, a23));
            }

        // cold path: fires only on diagonal tiles (and vanishing-probability outliers)
        if (__any(mx > thr)) {
            int col0w = ch * CHUNK + jj * 128 + wc * 64;
#pragma unroll
            for (int ti = 0; ti < 4; ++ti)
#pragma unroll
                for (int r = 0; r < 4; ++r) {
                    int grow = row0w + ti * 16 + quad * 4 + r;
                    float Mrow = diag10[grow];
                    float rs = 0.f;
#pragma unroll
                    for (int tj = 0; tj < 4; ++tj) {
                        int gcol = col0w + tj * 16 + l16;
                        float ev = __expf(acc[ti][tj][r] - Mrow);
                        rs += (grow == gcol) ? 0.f : ev;
                    }
                    rs += __shfl_xor(rs, 1, 16);
                    rs += __shfl_xor(rs, 2, 16);
                    rs += __shfl_xor(rs, 4, 16);
                    rs += __shfl_xor(rs, 8, 16);
                    if (l16 == 0) atomicAdd(&PS[grow], rs);
                }
        }

        asm volatile("s_waitcnt vmcnt(0)" ::: "memory");
        __syncthreads();
    }
}

// ---------------- k_final: posdot via S, log-term, reduce, ticket finalize -------
__global__ __launch_bounds__(256) void k_final(const float* __restrict__ F,
                                               const int* __restrict__ tgt,
                                               const float* __restrict__ diag10,
                                               const float* __restrict__ PS,
                                               const float* __restrict__ S,
                                               int* __restrict__ cnt,
                                               float* __restrict__ acc,
                                               float* __restrict__ out) {
    __shared__ float Ss[NCLS * KD];
    __shared__ int cs[NCLS];
    int t = threadIdx.x;
    for (int i = t; i < NCLS * KD; i += 256) Ss[i] = S[i];
    if (t < NCLS) cs[t] = cnt[t];
    __syncthreads();

    int g = t >> 2, q = t & 3;            // 4 lanes per row
    int row = blockIdx.x * 64 + g;
    int c = tgt[row];
    float dot = 0.f;
#pragma unroll
    for (int i = 0; i < 8; ++i) {
        float4 f = *(const float4*)(F + (size_t)row * KD + i * 16 + q * 4);
        float4 s = *(const float4*)(Ss + c * KD + i * 16 + q * 4);
        dot += f.x * s.x + f.y * s.y + f.z * s.z + f.w * s.w;
    }
    dot += __shfl_xor(dot, 1, 4);
    dot += __shfl_xor(dot, 2, 4);

    float mlp = 0.f;
    if (q == 0) {
        float M = diag10[row];
        float pp = 10.f * dot - M;            // sum over positives of logits
        float T = PS[row];                    // surviving shifted exp mass
        float np = (float)(cs[c] - 1);
        mlp = (np < 0.5f) ? 0.f : (pp - np * (M + __logf(T + 1e-20f))) / np;
    }
#pragma unroll
    for (int off = 32; off >= 1; off >>= 1) mlp += __shfl_xor(mlp, off);
    __shared__ float wsum[4];
    int lane = t & 63, w = t >> 6;
    if (lane == 0) wsum[w] = mlp;
    __syncthreads();
    if (t == 0) {
        atomicAdd(acc, (wsum[0] + wsum[1]) + (wsum[2] + wsum[3]));
        __threadfence();
        int old = atomicAdd(&cnt[12], 1);   // ticket
        if (old == (int)gridDim.x - 1) {
            float tot = atomicAdd(acc, 0.0f);   // coherent read of total
            double sp = 0.0, sn = 0.0;
            for (int cc = 0; cc < NCLS; ++cc) {
                double n = (double)cs[cc];
                sp += n * (n - 1.0);
                sn += n * ((double)N - n);
            }
            out[0] = (float)(-(0.1 / 0.07) * ((double)tot / (double)N));
            out[1] = (float)(sp / (double)N);
            out[2] = (float)(sn / (double)N);
        }
    }
}

extern "C" void kernel_launch(void* const* d_in, const int* in_sizes, int n_in,
                              void* d_out, int out_size, void* d_ws, size_t ws_size,
                              hipStream_t stream) {
    const float* F = (const float*)d_in[0];
    const int* tgt = (const int*)d_in[1];
    float* out = (float*)d_out;
    char* ws = (char*)d_ws;

    int* cnt = (int*)(ws);                       // 64 B (ticket at cnt[12])
    float* acc = (float*)(ws + 64);              // 4 B
    float* S = (float*)(ws + 128);               // 5120 B
    float* PS = (float*)(ws + 8192);             // 32 KiB  -> ends 40960
    float* diag10 = (float*)(ws + 65536);        // 32 KiB
    unsigned short* A10 = (unsigned short*)(ws + (1u << 20));   // 2 MiB
    unsigned short* B1 = (unsigned short*)(ws + (3u << 20));    // 2 MiB

    hipMemsetAsync(ws, 0, 40960, stream);        // cnt + acc + S + PS
    k_conv<<<576, 256, 0, stream>>>(F, tgt, diag10, A10, B1, S, cnt);
    k_pair<<<dim3(N / 128, NCH), 256, 0, stream>>>(A10, B1, diag10, PS);
    k_final<<<N / 64, 256, 0, stream>>>(F, tgt, diag10, PS, S, cnt, acc, out);
}